// Round 1
// baseline (583.208 us; speedup 1.0000x reference)
//
#include <hip/hip_runtime.h>

#define SNN_IN  8192
#define SNN_OUT 8192
#define SNN_THRESHOLD 50.0f

// One block per output row (8192 blocks x 256 threads).
// Phase 1: masked-GEMV row reduction -> current
// Phase 2: per-row spike/vmem/vth scalars (thread 0)
// Phase 3: eligibility trace update for the row (fused, no extra HBM pass)
__global__ __launch_bounds__(256) void snn_fused_kernel(
    const float* __restrict__ spike_in,   // [IN]
    const float* __restrict__ states,     // [OUT, IN]
    const float* __restrict__ v_mem,      // [OUT]
    const float* __restrict__ v_th,       // [OUT]
    const float* __restrict__ elig,       // [OUT, IN]
    const float* __restrict__ noise,      // [OUT]
    float* __restrict__ out_spikes,       // [OUT]
    float* __restrict__ out_vmem,         // [OUT]
    float* __restrict__ out_vth,          // [OUT]
    float* __restrict__ out_elig)         // [OUT, IN]
{
    const int row = blockIdx.x;
    const int tid = threadIdx.x;
    const size_t row_off4 = (size_t)row * (SNN_IN / 4);

    const float4* __restrict__ s4  = reinterpret_cast<const float4*>(states) + row_off4;
    const float4* __restrict__ sp4 = reinterpret_cast<const float4*>(spike_in);

    // ---- Phase 1: current[row] = sum_i (states[row,i] > 50) * spike[i] ----
    float partial = 0.0f;
    #pragma unroll
    for (int p = 0; p < SNN_IN / 4 / 256; ++p) {
        const int idx = p * 256 + tid;          // coalesced: consecutive lanes -> consecutive float4
        const float4 s  = s4[idx];
        const float4 sp = sp4[idx];
        partial += (s.x > SNN_THRESHOLD ? sp.x : 0.0f)
                 + (s.y > SNN_THRESHOLD ? sp.y : 0.0f)
                 + (s.z > SNN_THRESHOLD ? sp.z : 0.0f)
                 + (s.w > SNN_THRESHOLD ? sp.w : 0.0f);
    }

    // wave(64)-level butterfly reduce
    #pragma unroll
    for (int off = 32; off > 0; off >>= 1)
        partial += __shfl_down(partial, off, 64);

    __shared__ float wsum[4];
    __shared__ float s_spike;
    const int wave = tid >> 6;
    if ((tid & 63) == 0) wsum[wave] = partial;
    __syncthreads();

    // ---- Phase 2: per-row scalar state updates ----
    if (tid == 0) {
        const float current = wsum[0] + wsum[1] + wsum[2] + wsum[3];  // exact integer sum
        const float v_new = v_mem[row] * 0.8f + current + noise[row];
        const float spike = (v_new >= v_th[row]) ? 1.0f : 0.0f;
        out_spikes[row] = spike;
        out_vmem[row]   = v_new * (1.0f - spike) * 0.2f;
        const float vt  = v_th[row] + (spike - 0.05f) * 0.1f;
        out_vth[row]    = fminf(fmaxf(vt, 0.5f), 10.0f);
        s_spike = spike;
    }
    __syncthreads();
    const float spike = s_spike;

    // ---- Phase 3: elig_new[row,i] = clip(elig*0.95 + spike*sp[i], 0, 5) ----
    const float4* __restrict__ e4 = reinterpret_cast<const float4*>(elig) + row_off4;
    float4* __restrict__ o4       = reinterpret_cast<float4*>(out_elig) + row_off4;
    #pragma unroll
    for (int p = 0; p < SNN_IN / 4 / 256; ++p) {
        const int idx = p * 256 + tid;
        const float4 e  = e4[idx];
        const float4 sp = sp4[idx];
        float4 r;
        r.x = fminf(fmaxf(fmaf(e.x, 0.95f, spike * sp.x), 0.0f), 5.0f);
        r.y = fminf(fmaxf(fmaf(e.y, 0.95f, spike * sp.y), 0.0f), 5.0f);
        r.z = fminf(fmaxf(fmaf(e.z, 0.95f, spike * sp.z), 0.0f), 5.0f);
        r.w = fminf(fmaxf(fmaf(e.w, 0.95f, spike * sp.w), 0.0f), 5.0f);
        o4[idx] = r;
    }
}

extern "C" void kernel_launch(void* const* d_in, const int* in_sizes, int n_in,
                              void* d_out, int out_size, void* d_ws, size_t ws_size,
                              hipStream_t stream) {
    // setup_inputs() order: spike_input, states, v_mem, v_th, elig, noise
    const float* spike_in = (const float*)d_in[0];
    const float* states   = (const float*)d_in[1];
    const float* v_mem    = (const float*)d_in[2];
    const float* v_th     = (const float*)d_in[3];
    const float* elig     = (const float*)d_in[4];
    const float* noise    = (const float*)d_in[5];

    // Output tuple flattened in return order:
    // spikes [8192] | v_mem_new [8192] | v_th_new [8192] | elig_new [8192*8192]
    float* out            = (float*)d_out;
    float* out_spikes     = out;
    float* out_vmem       = out + SNN_OUT;
    float* out_vth        = out + 2 * SNN_OUT;
    float* out_elig       = out + 3 * SNN_OUT;

    snn_fused_kernel<<<SNN_OUT, 256, 0, stream>>>(
        spike_in, states, v_mem, v_th, elig, noise,
        out_spikes, out_vmem, out_vth, out_elig);
}